// Round 14
// baseline (250.846 us; speedup 1.0000x reference)
//
#include <hip/hip_runtime.h>

#define D_  256
#define K_  1024
#define HW_ 1024      // 32*32
#define N_  32768     // 32*HW_

// workspace layout (bytes)
#define WS_COUNTS  262144     // f32[1024]   (zeroed by vq_eprep)
#define WS_EMBSUM  266240     // f32[262144] (zeroed by vq_eprep)
#define WS_LOSS    1314816    // f32         (zeroed by vq_eprep)
#define WS_NSUM    1314820    // f32         (unused now; kept for layout)
#define WS_ENORM   1318924    // f32[1024]
#define WS_E16     1454096    // fp16(512*E)[1024*256] = 512 KiB (16B aligned)
#define WS_TOTAL   1978384

// output offsets (f32 elements): (z_q_st, loss, indices, new_emb, new_cs, new_es)
#define O_ZQ   0
#define O_LOSS 8388608
#define O_IDX  8388609
#define O_EMB  8421377
#define O_NCS  8683521
#define O_NES  8684545

typedef unsigned short u16;
typedef _Float16 f16x8 __attribute__((ext_vector_type(8)));  // 8 f16 = 4 VGPRs
typedef float f32x4 __attribute__((ext_vector_type(4)));

// pack two f32 -> two f16 (HW v_cvt_f16_f32, rne)
__device__ __forceinline__ unsigned f16x2pack(float a, float b) {
  union { _Float16 h; unsigned short u; } ca, cb;
  ca.h = (_Float16)a; cb.h = (_Float16)b;
  return (unsigned)ca.u | ((unsigned)cb.u << 16);
}

// numpy pairwise_sum of 256 squares: two 128-halves, 8 accumulators,
// combine ((r0+r1)+(r2+r3))+((r4+r5)+(r6+r7)). __f*_rn blocks FMA contraction.
__device__ __forceinline__ float pw256_sq(const float* __restrict__ p, int stride) {
  float tot0 = 0.f, tot1 = 0.f;
#pragma unroll
  for (int h = 0; h < 2; ++h) {
    const float* q = p + h * 128 * stride;
    float r[8];
#pragma unroll
    for (int j = 0; j < 8; ++j) { float x = q[j * stride]; r[j] = __fmul_rn(x, x); }
    for (int i = 8; i < 128; i += 8)
#pragma unroll
      for (int j = 0; j < 8; ++j) {
        float x = q[(i + j) * stride];
        r[j] = __fadd_rn(r[j], __fmul_rn(x, x));
      }
    float s = __fadd_rn(__fadd_rn(__fadd_rn(r[0], r[1]), __fadd_rn(r[2], r[3])),
                        __fadd_rn(__fadd_rn(r[4], r[5]), __fadd_rn(r[6], r[7])));
    if (h == 0) tot0 = s; else tot1 = s;
  }
  return __fadd_rn(tot0, tot1);
}

// ---------------- E prep: ||e||^2 (np order), E->fp16*512, workspace zeroing ----------------
// ROUND-14: widened 32 -> 256 blocks (more CUs on the convert+zero streams).
__global__ void vq_eprep(const float* __restrict__ E, float* __restrict__ enorm,
                         u16* __restrict__ E16, float* __restrict__ zero0) {
  int gid = blockIdx.x * 256 + threadIdx.x;   // 256 blocks -> 0..65535
  if (gid < K_) {
    float v = pw256_sq(E + gid * D_, 1);
    enorm[gid] = v;
  }
  unsigned* E16w = (unsigned*)E16;
  for (int wd = gid; wd < (K_ * D_ / 2); wd += 65536) {
    float2 x = *(const float2*)(E + 2 * wd);
    E16w[wd] = f16x2pack(512.0f * x.x, 512.0f * x.y);
  }
  // zero counts(4KB)+embsum(1MB)+loss+nsum: 65792 float4 + 2 floats
  float4 z4 = {0.f, 0.f, 0.f, 0.f};
  float4* zp = (float4*)zero0;
  for (int i = gid; i < 65792; i += 65536) zp[i] = z4;
  if (gid == 0) { zero0[263168] = 0.f; zero0[263169] = 0.f; }  // loss, nsum
}

// VALU-speed 16-lane min via DPP (quad_perm ^1, ^2, row_half_mirror, row_mirror)
template <int CTRL>
__device__ __forceinline__ float dppmin(float v) {
  int p = __builtin_amdgcn_update_dpp(0, __float_as_int(v), CTRL, 0xF, 0xF, true);
  return fminf(v, __int_as_float(p));
}

// Exact reference-numerics distance (np-order sequential fp32 FMA over d, then
// fl(fl(zn-2a)+en)); z row from LDS (contiguous f32), E row from global.
// en[] now points at GLOBAL enorm (L1-hot 4KB) — same values as the old LDS
// copy. Key=(score_bits<<32)|code -> LDS u64 atomicMin (block-final best;
// lowest code wins ties = np argmin). Called only AFTER the MFMA loop.
__device__ __forceinline__ void exact_update(
    const float* zrow, const float* __restrict__ E, int t, int c,
    const float* zn_s, const float* __restrict__ en, unsigned long long* best_s) {
  const float* ep = E + c * D_;
  float a = 0.f;
  for (int d0 = 0; d0 < 256; d0 += 8) {
    f32x4 z0 = *(const f32x4*)(zrow + d0);
    f32x4 z1 = *(const f32x4*)(zrow + d0 + 4);
    float4 e0 = *(const float4*)(ep + d0);
    float4 e1 = *(const float4*)(ep + d0 + 4);
    a = __fmaf_rn(z0[0], e0.x, a); a = __fmaf_rn(z0[1], e0.y, a);
    a = __fmaf_rn(z0[2], e0.z, a); a = __fmaf_rn(z0[3], e0.w, a);
    a = __fmaf_rn(z1[0], e1.x, a); a = __fmaf_rn(z1[1], e1.y, a);
    a = __fmaf_rn(z1[2], e1.z, a); a = __fmaf_rn(z1[3], e1.w, a);
  }
  float s = __fadd_rn(__fsub_rn(zn_s[t], __fmul_rn(2.0f, a)), en[c]);
  unsigned long long key = ((unsigned long long)__float_as_uint(s) << 32) | (unsigned)c;
  atomicMin(&best_s[t], key);
}

#define TCAP 96   // per-wave trigger list (expected ~24 used w/ fp16 margin)
#define ZP  260   // zs row pad: 260*4B = 1040 ≡ 0 mod 16 (b128-aligned rows)

// ---------------- FUSED dist + scatter (r13 body + fp16 fragment tile) ----------------
// 1024 blocks x 256 thr. ROUND-14 (surgical; structure otherwise byte-frozen):
// phase A's fragment reads move from the f32 zs tile (4x ds_read_b128/MSTEP,
// 8-way bank conflicts = 6.27M/dispatch, + 16 v_cvt/MSTEP — measured ~40-60us
// of DS/VALU serialization per CU) to a 16KB fp16 tile in r8's PROVEN
// conflict-free [kb][tok][8d] layout (2x b128, 13K conflicts, zero cvt).
// zs stays for pw256/exact/phase B (bit-exact paths). en_s LDS copy dropped to
// pay for zt16 (enorm reads become L1-hot global scalars). LDS ~52KB ->
// 3 blocks/CU (was 4) — DS savings >> occupancy loss.
// Margin M = 2^-8*sqrt(zn*en_max)+5e-4 (2x the rigorous two-sided fp16 bound)
// -> reference argmin always triggers; exact fp32 chain (np order) decides.
__global__ __launch_bounds__(256, 4) void vq_main(
    const float* __restrict__ z, const float* __restrict__ E,
    const u16* __restrict__ E16, const float* __restrict__ enorm,
    float* __restrict__ embsum, float* __restrict__ loss_sum,
    float* __restrict__ counts, float* __restrict__ out_zq,
    float* __restrict__ out_idx) {
  __shared__ __align__(16) float zs[32 * ZP];            // 33280 B, [tok][d]
  __shared__ __align__(16) u16 zt16[32 * 32 * 8];        // 16 KiB, [kb][tok][8d]
  __shared__ float zn_s[32];
  __shared__ float mg_s[32];
  __shared__ unsigned rmin_s[32];                         // bits of (min ph)+4.0
  __shared__ unsigned long long best_s[32];
  __shared__ unsigned tcount[4];
  __shared__ unsigned tlist[4][TCAP];                     // 1.5 KiB
  __shared__ float wred[4];

  const int tid = threadIdx.x;
  const int tile = blockIdx.x;               // 0..1023
  const int bimg = tile >> 5;
  const int hw0 = (tile & 31) << 5;          // 32 tokens
  const float* zb = z + bimg * (D_ * HW_) + hw0;
  const int n0 = bimg * HW_ + hw0;

  // stage z f32 -> zs[t][d] (coalesced float4 global reads, scalar LDS writes)
#pragma unroll
  for (int r = 0; r < 8; ++r) {
    int ii = r * 256 + tid;
    int d = ii >> 3, t4 = (ii & 7) * 4;
    float4 v = *(const float4*)(zb + d * HW_ + t4);
    zs[(t4 + 0) * ZP + d] = v.x; zs[(t4 + 1) * ZP + d] = v.y;
    zs[(t4 + 2) * ZP + d] = v.z; zs[(t4 + 3) * ZP + d] = v.w;
  }
  // stage z -> fp16 tile (r8-proven layout; rne cvt = same values as before).
  // Global reads are L1-hot (just read by the f32 staging above).
  {
    const int tok = tid & 31;
    const int kbase = (tid >> 5) * 4;        // 8 groups x 4 kb = 32 kb
    for (int r = 0; r < 4; ++r) {
      int kb = kbase + r;
      unsigned pk[4];
#pragma unroll
      for (int j = 0; j < 4; ++j) {
        float x0 = zb[(kb * 8 + 2 * j) * HW_ + tok];
        float x1 = zb[(kb * 8 + 2 * j + 1) * HW_ + tok];
        pk[j] = f16x2pack(x0, x1);
      }
      uint4 wv; wv.x = pk[0]; wv.y = pk[1]; wv.z = pk[2]; wv.w = pk[3];
      *(uint4*)(zt16 + kb * 256 + tok * 8) = wv;       // 16B, conflict-free
    }
  }
  // local en_max over global enorm (bit-identical to the old LDS-copy max)
  {
    float emx = 0.f;
    for (int i = tid; i < K_; i += 256) emx = fmaxf(emx, enorm[i]);
#pragma unroll
    for (int o = 32; o > 0; o >>= 1) emx = fmaxf(emx, __shfl_down(emx, o, 64));
    if ((tid & 63) == 0) wred[tid >> 6] = emx;
  }
  if (tid < 4) tcount[tid] = 0;
  __syncthreads();
  if (tid < 32) {
    float zn = pw256_sq(&zs[tid * ZP], 1);   // np order, bit-identical values
    zn_s[tid] = zn;
    float em = fmaxf(fmaxf(wred[0], wred[1]), fmaxf(wred[2], wred[3]));
    mg_s[tid] = 0.00390625f * sqrtf(zn * em) + 5e-4f;  // fp16 margin (proven safe)
    rmin_s[tid] = 0xFFFFFFFFu;
    best_s[tid] = ~0ull;
  }
  __syncthreads();

  const int lane = tid & 63;
  const int w = tid >> 6;
  const int l15 = lane & 15, g = lane >> 4;
  const int cw = w * 256;                    // wave's code base
  const u16* Eb = E16 + (unsigned)(cw + l15) * D_ + g * 8;

  f16x8 efA[2], efB[2];
#pragma unroll
  for (int n = 0; n < 2; ++n)
    efA[n] = *(const f16x8*)(Eb + n * 16 * D_);          // prime: s=0 (ch0,kk0)

  f32x4 acc[2][2];

// one MFMA step: ef ping-pong (dist-1; best-measured); zf from the conflict-
// free fp16 tile (2 b128, consecutive 16B slots per 16-lane group, no cvt).
// No branches, no calls in the loop.
#define MSTEP(S, EFU, EFF, SN)                                                   \
  {                                                                              \
    const int kk_ = (S) & 7;                                                     \
    {                                                                            \
      const int cn_ = (SN) >> 3, kn_ = (SN) & 7;                                 \
      _Pragma("unroll")                                                          \
      for (int n = 0; n < 2; ++n)                                                \
        EFF[n] = *(const f16x8*)(Eb + (cn_ * 32 + n * 16) * D_ + kn_ * 32);      \
    }                                                                            \
    f16x8 zf_[2];                                                                \
    _Pragma("unroll")                                                            \
    for (int m = 0; m < 2; ++m)                                                  \
      zf_[m] = *(const f16x8*)(zt16 + (kk_ * 4 + g) * 256 + (m * 16 + l15) * 8); \
    _Pragma("unroll")                                                            \
    for (int m = 0; m < 2; ++m)                                                  \
      _Pragma("unroll")                                                          \
      for (int n = 0; n < 2; ++n)                                                \
        acc[m][n] = __builtin_amdgcn_mfma_f32_16x16x32_f16(zf_[m], EFU[n],       \
                                                           acc[m][n], 0, 0, 0);  \
  }

  for (int s2 = 0; s2 < 64; s2 += 2) {      // 8 chunks x 8 kk
    if ((s2 & 7) == 0) {
      f32x4 z4 = {0.f, 0.f, 0.f, 0.f};
#pragma unroll
      for (int m = 0; m < 2; ++m)
#pragma unroll
        for (int n = 0; n < 2; ++n) acc[m][n] = z4;
    }
    MSTEP(s2, efA, efB, s2 + 1)
    MSTEP(s2 + 1, efB, efA, (s2 + 2) & 63)   // tail wrap value never consumed
    if ((s2 & 7) == 6) {                     // chunk end
      const int cb = cw + (s2 >> 3) * 32;
      // ph = en - 2*(A/512) = fma(-1/256, A, en); D: col=l15(code), row=g*4+r(tok)
      float enc[2];
#pragma unroll
      for (int n = 0; n < 2; ++n) enc[n] = enorm[cb + n * 16 + l15];  // L1-hot
#pragma unroll
      for (int m = 0; m < 2; ++m)
#pragma unroll
        for (int n = 0; n < 2; ++n)
#pragma unroll
          for (int r = 0; r < 4; ++r)
            acc[m][n][r] = __builtin_fmaf(-0.00390625f, acc[m][n][r], enc[n]);
#pragma unroll
      for (int m = 0; m < 2; ++m)
#pragma unroll
        for (int r = 0; r < 4; ++r) {
          float v = fminf(acc[m][0][r], acc[m][1][r]);
          v = dppmin<0xB1>(v);     // ^1
          v = dppmin<0x4E>(v);     // ^2
          v = dppmin<0x141>(v);    // row_half_mirror
          v = dppmin<0x140>(v);    // row_mirror
          if (l15 == 0) atomicMin(&rmin_s[m * 16 + g * 4 + r], __float_as_uint(v + 4.0f));
        }
#pragma unroll
      for (int m = 0; m < 2; ++m)
#pragma unroll
        for (int r = 0; r < 4; ++r) {
          int t = m * 16 + g * 4 + r;
          float thr = (__uint_as_float(rmin_s[t]) - 4.0f) + mg_s[t];
#pragma unroll
          for (int n = 0; n < 2; ++n) {
            if (acc[m][n][r] <= thr) {
              unsigned pos = atomicAdd(&tcount[w], 1u);
              if (pos < TCAP)
                tlist[w][pos] = ((unsigned)t << 16) | (unsigned)(cb + n * 16 + l15);
            }
          }
        }
    }
  }
#undef MSTEP

  // drain own wave's triggers: exact recompute (LDS z row + global E) -> best_s
  {
    unsigned cnt = tcount[w];
    if (cnt <= TCAP) {
      for (unsigned basei = 0; basei < cnt; basei += 64) {
        unsigned i = basei + (unsigned)lane;
        if (i < cnt) {
          unsigned e = tlist[w][i];
          int t = (int)(e >> 16), c = (int)(e & 1023u);
          exact_update(&zs[t * ZP], E, t, c, zn_s, enorm, best_s);
        }
      }
    } else {
      // overflow (astronomically rare): exact-verify wave's whole 32x256 tile
      for (unsigned i = (unsigned)lane; i < 32u * 256u; i += 64) {
        int t = (int)(i >> 8), c = cw + (int)(i & 255u);
        exact_update(&zs[t * ZP], E, t, c, zn_s, enorm, best_s);
      }
    }
  }
  __syncthreads();   // best_s final; zs reads done -> phase B may overwrite

  // ---------------- phase B: scatter body on the same LDS tile ----------------
  if (tid < 32) {
    int k = (int)(best_s[tid] & 1023ull);
    out_idx[n0 + tid] = (float)k;
    atomicAdd(&counts[k], 1.0f);
  }
  float lsum = 0.f;
  for (int tt = 0; tt < 8; ++tt) {
    int t = w * 8 + tt;
    int k = (int)(best_s[t] & 1023ull);    // wave-uniform
    const float* Er = E + k * D_;
    float* es = embsum + k * D_;
#pragma unroll
    for (int i = 0; i < 4; ++i) {
      int d = i * 64 + lane;
      float e = Er[d];
      float zv = zs[t * ZP + d];           // unique (t,d) owner -> safe in-place
      float df = __fsub_rn(zv, e);
      lsum += df * df;
      zs[t * ZP + d] = __fadd_rn(zv, __fsub_rn(e, zv));  // ref: z + (z_q - z)
      atomicAdd(es + d, zv);
    }
  }
#pragma unroll
  for (int o = 32; o > 0; o >>= 1) lsum += __shfl_down(lsum, o, 64);
  if (lane == 0) wred[w] = lsum;
  __syncthreads();
  if (tid == 0) atomicAdd(loss_sum, wred[0] + wred[1] + wred[2] + wred[3]);

  float* ob = out_zq + bimg * (D_ * HW_) + hw0;
#pragma unroll 4
  for (int r = 0; r < 32; ++r) {
    int d = r * 8 + (tid >> 5);
    int t = tid & 31;
    ob[d * HW_ + t] = zs[t * ZP + d];      // coalesced 128B-chunk f32 stores
  }
}

// ---------------- fused EMA finalize: newcs + nsum + loss + newemb ----------------
// 1024 blocks x 256 thr. Every block redundantly computes the full 1024-element
// nsum (identical code + data + order in each block -> bit-identical n across
// blocks; ~8KB of L2-broadcast reads).
__global__ void vq_newfin(const float* __restrict__ cs_in, const float* __restrict__ counts,
                          const float* __restrict__ es_in, const float* __restrict__ embsum,
                          const float* __restrict__ loss_sum,
                          float* __restrict__ out_loss, float* __restrict__ out_ncs,
                          float* __restrict__ out_emb, float* __restrict__ out_nes) {
  __shared__ float nred[4];
  const int k = blockIdx.x, d = threadIdx.x;
  float s = 0.f;
  float myv[4];
#pragma unroll
  for (int i = 0; i < 4; ++i) {
    int idx = i * 256 + d;
    float v = __fadd_rn(__fmul_rn(0.99f, cs_in[idx]), __fmul_rn(0.01f, counts[idx]));
    myv[i] = v;
    s += v;
  }
#pragma unroll
  for (int o = 32; o > 0; o >>= 1) s += __shfl_down(s, o, 64);
  if ((d & 63) == 0) nred[d >> 6] = s;
  __syncthreads();
  const float n = (nred[0] + nred[1]) + (nred[2] + nred[3]);
  if (d == (k & 255)) out_ncs[k] = myv[k >> 8];      // block k owns element k
  if (k == 0 && d == 0) out_loss[0] = loss_sum[0] * (1.0f / 8388608.0f);
  float vk = __fadd_rn(__fmul_rn(0.99f, cs_in[k]), __fmul_rn(0.01f, counts[k]));
  float cs = (vk + 1e-5f) / (n + 1024.0f * 1e-5f) * n;   // ref formula order
  float es = __fadd_rn(__fmul_rn(0.99f, es_in[k * D_ + d]),
                       __fmul_rn(0.01f, embsum[k * D_ + d]));
  out_nes[k * D_ + d] = es;
  out_emb[k * D_ + d] = es / cs;
}

extern "C" void kernel_launch(void* const* d_in, const int* in_sizes, int n_in,
                              void* d_out, int out_size, void* d_ws, size_t ws_size,
                              hipStream_t stream) {
  (void)in_sizes; (void)n_in; (void)out_size; (void)ws_size;
  const float* z       = (const float*)d_in[0];
  const float* E       = (const float*)d_in[1];
  const float* ema_cs  = (const float*)d_in[2];
  const float* ema_es  = (const float*)d_in[3];
  float* out = (float*)d_out;
  char* ws = (char*)d_ws;
  float* counts = (float*)(ws + WS_COUNTS);
  float* embsum = (float*)(ws + WS_EMBSUM);
  float* loss_s = (float*)(ws + WS_LOSS);
  float* enorm  = (float*)(ws + WS_ENORM);
  u16*   e16    = (u16*)(ws + WS_E16);

  // 3 dispatches: eprep(+zero) -> main -> newfin.
  vq_eprep<<<dim3(256), dim3(256), 0, stream>>>(E, enorm, e16, counts);
  vq_main<<<dim3(1024), dim3(256), 0, stream>>>(z, E, e16, enorm,
                                                embsum, loss_s, counts,
                                                out + O_ZQ, out + O_IDX);
  vq_newfin<<<dim3(K_), dim3(256), 0, stream>>>(ema_cs, counts, ema_es, embsum,
                                                loss_s, out + O_LOSS, out + O_NCS,
                                                out + O_EMB, out + O_NES);
}

// Round 15
// 209.254 us; speedup vs baseline: 1.1988x; 1.1988x over previous
//
#include <hip/hip_runtime.h>

#define D_  256
#define K_  1024
#define HW_ 1024      // 32*32
#define N_  32768     // 32*HW_

// workspace layout (bytes)
#define WS_COUNTS  262144     // f32[1024]   (zeroed by vq_eprep)
#define WS_EMBSUM  266240     // f32[262144] (zeroed by vq_eprep)
#define WS_LOSS    1314816    // f32         (zeroed by vq_eprep)
#define WS_NSUM    1314820    // f32         (unused now; kept for layout)
#define WS_ENORM   1318924    // f32[1024]
#define WS_E16     1454096    // fp16(512*E)[1024*256] = 512 KiB (16B aligned)
#define WS_TOTAL   1978384

// output offsets (f32 elements): (z_q_st, loss, indices, new_emb, new_cs, new_es)
#define O_ZQ   0
#define O_LOSS 8388608
#define O_IDX  8388609
#define O_EMB  8421377
#define O_NCS  8683521
#define O_NES  8684545

typedef unsigned short u16;
typedef _Float16 f16x8 __attribute__((ext_vector_type(8)));  // 8 f16 = 4 VGPRs
typedef float f32x4 __attribute__((ext_vector_type(4)));

// pack two f32 -> two f16 (HW v_cvt_f16_f32, rne)
__device__ __forceinline__ unsigned f16x2pack(float a, float b) {
  union { _Float16 h; unsigned short u; } ca, cb;
  ca.h = (_Float16)a; cb.h = (_Float16)b;
  return (unsigned)ca.u | ((unsigned)cb.u << 16);
}

// numpy pairwise_sum of 256 squares: two 128-halves, 8 accumulators,
// combine ((r0+r1)+(r2+r3))+((r4+r5)+(r6+r7)). __f*_rn blocks FMA contraction.
__device__ __forceinline__ float pw256_sq(const float* __restrict__ p, int stride) {
  float tot0 = 0.f, tot1 = 0.f;
#pragma unroll
  for (int h = 0; h < 2; ++h) {
    const float* q = p + h * 128 * stride;
    float r[8];
#pragma unroll
    for (int j = 0; j < 8; ++j) { float x = q[j * stride]; r[j] = __fmul_rn(x, x); }
    for (int i = 8; i < 128; i += 8)
#pragma unroll
      for (int j = 0; j < 8; ++j) {
        float x = q[(i + j) * stride];
        r[j] = __fadd_rn(r[j], __fmul_rn(x, x));
      }
    float s = __fadd_rn(__fadd_rn(__fadd_rn(r[0], r[1]), __fadd_rn(r[2], r[3])),
                        __fadd_rn(__fadd_rn(r[4], r[5]), __fadd_rn(r[6], r[7])));
    if (h == 0) tot0 = s; else tot1 = s;
  }
  return __fadd_rn(tot0, tot1);
}

// ---------------- E prep: ||e||^2 (np order), E->fp16*512, workspace zeroing ----------------
// 256 blocks (r14 widening, kept — independent of the vq_main revert).
__global__ void vq_eprep(const float* __restrict__ E, float* __restrict__ enorm,
                         u16* __restrict__ E16, float* __restrict__ zero0) {
  int gid = blockIdx.x * 256 + threadIdx.x;   // 256 blocks -> 0..65535
  if (gid < K_) {
    float v = pw256_sq(E + gid * D_, 1);
    enorm[gid] = v;
  }
  unsigned* E16w = (unsigned*)E16;
  for (int wd = gid; wd < (K_ * D_ / 2); wd += 65536) {
    float2 x = *(const float2*)(E + 2 * wd);
    E16w[wd] = f16x2pack(512.0f * x.x, 512.0f * x.y);
  }
  // zero counts(4KB)+embsum(1MB)+loss+nsum: 65792 float4 + 2 floats
  float4 z4 = {0.f, 0.f, 0.f, 0.f};
  float4* zp = (float4*)zero0;
  for (int i = gid; i < 65792; i += 65536) zp[i] = z4;
  if (gid == 0) { zero0[263168] = 0.f; zero0[263169] = 0.f; }  // loss, nsum
}

// VALU-speed 16-lane min via DPP (quad_perm ^1, ^2, row_half_mirror, row_mirror)
template <int CTRL>
__device__ __forceinline__ float dppmin(float v) {
  int p = __builtin_amdgcn_update_dpp(0, __float_as_int(v), CTRL, 0xF, 0xF, true);
  return fminf(v, __int_as_float(p));
}

// Exact reference-numerics distance (np-order sequential fp32 FMA over d, then
// fl(fl(zn-2a)+en)); z row from LDS (contiguous f32), E row from global.
// Key=(score_bits<<32)|code -> LDS u64 atomicMin (block-final best; lowest
// code wins ties = np argmin). forceinline: only 2 call sites, both AFTER the
// MFMA loop (round-3 lesson: no calls with live acc/ef).
__device__ __forceinline__ void exact_update(
    const float* zrow, const float* __restrict__ E, int t, int c,
    const float* zn_s, const float* en_s, unsigned long long* best_s) {
  const float* ep = E + c * D_;
  float a = 0.f;
  for (int d0 = 0; d0 < 256; d0 += 8) {
    f32x4 z0 = *(const f32x4*)(zrow + d0);
    f32x4 z1 = *(const f32x4*)(zrow + d0 + 4);
    float4 e0 = *(const float4*)(ep + d0);
    float4 e1 = *(const float4*)(ep + d0 + 4);
    a = __fmaf_rn(z0[0], e0.x, a); a = __fmaf_rn(z0[1], e0.y, a);
    a = __fmaf_rn(z0[2], e0.z, a); a = __fmaf_rn(z0[3], e0.w, a);
    a = __fmaf_rn(z1[0], e1.x, a); a = __fmaf_rn(z1[1], e1.y, a);
    a = __fmaf_rn(z1[2], e1.z, a); a = __fmaf_rn(z1[3], e1.w, a);
  }
  float s = __fadd_rn(__fsub_rn(zn_s[t], __fmul_rn(2.0f, a)), en_s[c]);
  unsigned long long key = ((unsigned long long)__float_as_uint(s) << 32) | (unsigned)c;
  atomicMin(&best_s[t], key);
}

#define TCAP 96   // per-wave trigger list (expected ~24 used w/ fp16 margin)
#define ZP  260   // zs row pad: 260*4B = 1040 ≡ 0 mod 16 (b128-aligned rows)

// ---------------- FUSED dist + scatter (round-13 kernel, byte-identical) ----------------
// 1024 blocks x 256 thr, ~39 KB LDS -> 4 blocks/CU. Block = 32 tokens x ALL
// 1024 codes => best is block-final => scatter fuses in.
// FROZEN at the r13 body (125.6us, VGPR=64, no spill). The measured triangle:
//   r13 (zs only):      6.27M conflicts, 4 blk/CU -> 125.6us   <- optimum
//   r14 (zs+zt16):      2.05M conflicts, 2 blk/CU -> 167.3us   (occupancy loss)
//   r11 (zt16 only):    RA ghost -> VGPR 40 + 296MB scratch spill
// Phase A: MFMA fp16 approx scores (z cvt'd f32->f16 on the fly from the LDS
// f32 tile), per-token running min, margin-gated trigger list, exact fp32
// re-verify into LDS best_s. Margin M = 2^-8*sqrt(zn*en_max)+5e-4 (2x the
// rigorous two-sided fp16 bound) -> reference argmin always triggers.
// Phase B: scatter body on the same LDS tile (loss, z_q_st in-place,
// embsum atomics, counts, idx).
__global__ __launch_bounds__(256, 4) void vq_main(
    const float* __restrict__ z, const float* __restrict__ E,
    const u16* __restrict__ E16, const float* __restrict__ enorm,
    float* __restrict__ embsum, float* __restrict__ loss_sum,
    float* __restrict__ counts, float* __restrict__ out_zq,
    float* __restrict__ out_idx) {
  __shared__ __align__(16) float zs[32 * ZP];            // 33280 B, [tok][d]
  __shared__ float en_s[K_];                              // 4 KiB
  __shared__ float zn_s[32];
  __shared__ float mg_s[32];
  __shared__ unsigned rmin_s[32];                         // bits of (min ph)+4.0
  __shared__ unsigned long long best_s[32];
  __shared__ unsigned tcount[4];
  __shared__ unsigned tlist[4][TCAP];                     // 1.5 KiB
  __shared__ float wred[4];

  const int tid = threadIdx.x;
  const int tile = blockIdx.x;               // 0..1023
  const int bimg = tile >> 5;
  const int hw0 = (tile & 31) << 5;          // 32 tokens
  const float* zb = z + bimg * (D_ * HW_) + hw0;
  const int n0 = bimg * HW_ + hw0;

  // stage z f32 -> zs[t][d] (coalesced float4 global reads, scalar LDS writes)
#pragma unroll
  for (int r = 0; r < 8; ++r) {
    int ii = r * 256 + tid;
    int d = ii >> 3, t4 = (ii & 7) * 4;
    float4 v = *(const float4*)(zb + d * HW_ + t4);
    zs[(t4 + 0) * ZP + d] = v.x; zs[(t4 + 1) * ZP + d] = v.y;
    zs[(t4 + 2) * ZP + d] = v.z; zs[(t4 + 3) * ZP + d] = v.w;
  }
  // en_s load + local en_max (bit-identical max, no cross-dispatch atomic)
  {
    float emx = 0.f;
    for (int i = tid; i < K_; i += 256) {
      float v = enorm[i];
      en_s[i] = v;
      emx = fmaxf(emx, v);
    }
#pragma unroll
    for (int o = 32; o > 0; o >>= 1) emx = fmaxf(emx, __shfl_down(emx, o, 64));
    if ((tid & 63) == 0) wred[tid >> 6] = emx;
  }
  if (tid < 4) tcount[tid] = 0;
  __syncthreads();
  if (tid < 32) {
    float zn = pw256_sq(&zs[tid * ZP], 1);   // np order, bit-identical values
    zn_s[tid] = zn;
    float em = fmaxf(fmaxf(wred[0], wred[1]), fmaxf(wred[2], wred[3]));
    mg_s[tid] = 0.00390625f * sqrtf(zn * em) + 5e-4f;  // fp16 margin (proven safe)
    rmin_s[tid] = 0xFFFFFFFFu;
    best_s[tid] = ~0ull;
  }
  __syncthreads();

  const int lane = tid & 63;
  const int w = tid >> 6;
  const int l15 = lane & 15, g = lane >> 4;
  const int cw = w * 256;                    // wave's code base
  const u16* Eb = E16 + (unsigned)(cw + l15) * D_ + g * 8;

  f16x8 efA[2], efB[2];
#pragma unroll
  for (int n = 0; n < 2; ++n)
    efA[n] = *(const f16x8*)(Eb + n * 16 * D_);          // prime: s=0 (ch0,kk0)

  f32x4 acc[2][2];

// one MFMA step: ef ping-pong (dist-1; best-measured), z fragment read as f32
// from zs + cvt to fp16 (same rne values as the old pre-converted tile).
// No branches, no calls in the loop.
#define MSTEP(S, EFU, EFF, SN)                                                   \
  {                                                                              \
    const int kk_ = (S) & 7;                                                     \
    {                                                                            \
      const int cn_ = (SN) >> 3, kn_ = (SN) & 7;                                 \
      _Pragma("unroll")                                                          \
      for (int n = 0; n < 2; ++n)                                                \
        EFF[n] = *(const f16x8*)(Eb + (cn_ * 32 + n * 16) * D_ + kn_ * 32);      \
    }                                                                            \
    f16x8 zf_[2];                                                                \
    _Pragma("unroll")                                                            \
    for (int m = 0; m < 2; ++m) {                                                \
      const float* zr = zs + (m * 16 + l15) * ZP + kk_ * 32 + g * 8;             \
      f32x4 lo = *(const f32x4*)zr;                                              \
      f32x4 hi = *(const f32x4*)(zr + 4);                                        \
      f16x8 zc;                                                                  \
      _Pragma("unroll")                                                          \
      for (int j = 0; j < 4; ++j) {                                              \
        zc[j] = (_Float16)lo[j]; zc[4 + j] = (_Float16)hi[j];                    \
      }                                                                          \
      zf_[m] = zc;                                                               \
    }                                                                            \
    _Pragma("unroll")                                                            \
    for (int m = 0; m < 2; ++m)                                                  \
      _Pragma("unroll")                                                          \
      for (int n = 0; n < 2; ++n)                                                \
        acc[m][n] = __builtin_amdgcn_mfma_f32_16x16x32_f16(zf_[m], EFU[n],       \
                                                           acc[m][n], 0, 0, 0);  \
  }

  for (int s2 = 0; s2 < 64; s2 += 2) {      // 8 chunks x 8 kk
    if ((s2 & 7) == 0) {
      f32x4 z4 = {0.f, 0.f, 0.f, 0.f};
#pragma unroll
      for (int m = 0; m < 2; ++m)
#pragma unroll
        for (int n = 0; n < 2; ++n) acc[m][n] = z4;
    }
    MSTEP(s2, efA, efB, s2 + 1)
    MSTEP(s2 + 1, efB, efA, (s2 + 2) & 63)   // tail wrap value never consumed
    if ((s2 & 7) == 6) {                     // chunk end
      const int cb = cw + (s2 >> 3) * 32;
      // ph = en - 2*(A/512) = fma(-1/256, A, en); D: col=l15(code), row=g*4+r(tok)
      float enc[2];
#pragma unroll
      for (int n = 0; n < 2; ++n) enc[n] = en_s[cb + n * 16 + l15];
#pragma unroll
      for (int m = 0; m < 2; ++m)
#pragma unroll
        for (int n = 0; n < 2; ++n)
#pragma unroll
          for (int r = 0; r < 4; ++r)
            acc[m][n][r] = __builtin_fmaf(-0.00390625f, acc[m][n][r], enc[n]);
#pragma unroll
      for (int m = 0; m < 2; ++m)
#pragma unroll
        for (int r = 0; r < 4; ++r) {
          float v = fminf(acc[m][0][r], acc[m][1][r]);
          v = dppmin<0xB1>(v);     // ^1
          v = dppmin<0x4E>(v);     // ^2
          v = dppmin<0x141>(v);    // row_half_mirror
          v = dppmin<0x140>(v);    // row_mirror
          if (l15 == 0) atomicMin(&rmin_s[m * 16 + g * 4 + r], __float_as_uint(v + 4.0f));
        }
#pragma unroll
      for (int m = 0; m < 2; ++m)
#pragma unroll
        for (int r = 0; r < 4; ++r) {
          int t = m * 16 + g * 4 + r;
          float thr = (__uint_as_float(rmin_s[t]) - 4.0f) + mg_s[t];
#pragma unroll
          for (int n = 0; n < 2; ++n) {
            if (acc[m][n][r] <= thr) {
              unsigned pos = atomicAdd(&tcount[w], 1u);
              if (pos < TCAP)
                tlist[w][pos] = ((unsigned)t << 16) | (unsigned)(cb + n * 16 + l15);
            }
          }
        }
    }
  }
#undef MSTEP

  // drain own wave's triggers: exact recompute (LDS z row + global E) -> best_s
  {
    unsigned cnt = tcount[w];
    if (cnt <= TCAP) {
      for (unsigned basei = 0; basei < cnt; basei += 64) {
        unsigned i = basei + (unsigned)lane;
        if (i < cnt) {
          unsigned e = tlist[w][i];
          int t = (int)(e >> 16), c = (int)(e & 1023u);
          exact_update(&zs[t * ZP], E, t, c, zn_s, en_s, best_s);
        }
      }
    } else {
      // overflow (astronomically rare): exact-verify wave's whole 32x256 tile
      for (unsigned i = (unsigned)lane; i < 32u * 256u; i += 64) {
        int t = (int)(i >> 8), c = cw + (int)(i & 255u);
        exact_update(&zs[t * ZP], E, t, c, zn_s, en_s, best_s);
      }
    }
  }
  __syncthreads();   // best_s final; zs reads done -> phase B may overwrite

  // ---------------- phase B: scatter body on the same LDS tile ----------------
  if (tid < 32) {
    int k = (int)(best_s[tid] & 1023ull);
    out_idx[n0 + tid] = (float)k;
    atomicAdd(&counts[k], 1.0f);
  }
  float lsum = 0.f;
  for (int tt = 0; tt < 8; ++tt) {
    int t = w * 8 + tt;
    int k = (int)(best_s[t] & 1023ull);    // wave-uniform
    const float* Er = E + k * D_;
    float* es = embsum + k * D_;
#pragma unroll
    for (int i = 0; i < 4; ++i) {
      int d = i * 64 + lane;
      float e = Er[d];
      float zv = zs[t * ZP + d];           // unique (t,d) owner -> safe in-place
      float df = __fsub_rn(zv, e);
      lsum += df * df;
      zs[t * ZP + d] = __fadd_rn(zv, __fsub_rn(e, zv));  // ref: z + (z_q - z)
      atomicAdd(es + d, zv);
    }
  }
#pragma unroll
  for (int o = 32; o > 0; o >>= 1) lsum += __shfl_down(lsum, o, 64);
  if (lane == 0) wred[w] = lsum;
  __syncthreads();
  if (tid == 0) atomicAdd(loss_sum, wred[0] + wred[1] + wred[2] + wred[3]);

  float* ob = out_zq + bimg * (D_ * HW_) + hw0;
#pragma unroll 4
  for (int r = 0; r < 32; ++r) {
    int d = r * 8 + (tid >> 5);
    int t = tid & 31;
    ob[d * HW_ + t] = zs[t * ZP + d];      // coalesced 128B-chunk f32 stores
  }
}

// ---------------- fused EMA finalize: newcs + nsum + loss + newemb ----------------
// 1024 blocks x 256 thr. Every block redundantly computes the full 1024-element
// nsum (identical code + data + order in each block -> bit-identical n across
// blocks; ~8KB of L2-broadcast reads).
__global__ void vq_newfin(const float* __restrict__ cs_in, const float* __restrict__ counts,
                          const float* __restrict__ es_in, const float* __restrict__ embsum,
                          const float* __restrict__ loss_sum,
                          float* __restrict__ out_loss, float* __restrict__ out_ncs,
                          float* __restrict__ out_emb, float* __restrict__ out_nes) {
  __shared__ float nred[4];
  const int k = blockIdx.x, d = threadIdx.x;
  float s = 0.f;
  float myv[4];
#pragma unroll
  for (int i = 0; i < 4; ++i) {
    int idx = i * 256 + d;
    float v = __fadd_rn(__fmul_rn(0.99f, cs_in[idx]), __fmul_rn(0.01f, counts[idx]));
    myv[i] = v;
    s += v;
  }
#pragma unroll
  for (int o = 32; o > 0; o >>= 1) s += __shfl_down(s, o, 64);
  if ((d & 63) == 0) nred[d >> 6] = s;
  __syncthreads();
  const float n = (nred[0] + nred[1]) + (nred[2] + nred[3]);
  if (d == (k & 255)) out_ncs[k] = myv[k >> 8];      // block k owns element k
  if (k == 0 && d == 0) out_loss[0] = loss_sum[0] * (1.0f / 8388608.0f);
  float vk = __fadd_rn(__fmul_rn(0.99f, cs_in[k]), __fmul_rn(0.01f, counts[k]));
  float cs = (vk + 1e-5f) / (n + 1024.0f * 1e-5f) * n;   // ref formula order
  float es = __fadd_rn(__fmul_rn(0.99f, es_in[k * D_ + d]),
                       __fmul_rn(0.01f, embsum[k * D_ + d]));
  out_nes[k * D_ + d] = es;
  out_emb[k * D_ + d] = es / cs;
}

extern "C" void kernel_launch(void* const* d_in, const int* in_sizes, int n_in,
                              void* d_out, int out_size, void* d_ws, size_t ws_size,
                              hipStream_t stream) {
  (void)in_sizes; (void)n_in; (void)out_size; (void)ws_size;
  const float* z       = (const float*)d_in[0];
  const float* E       = (const float*)d_in[1];
  const float* ema_cs  = (const float*)d_in[2];
  const float* ema_es  = (const float*)d_in[3];
  float* out = (float*)d_out;
  char* ws = (char*)d_ws;
  float* counts = (float*)(ws + WS_COUNTS);
  float* embsum = (float*)(ws + WS_EMBSUM);
  float* loss_s = (float*)(ws + WS_LOSS);
  float* enorm  = (float*)(ws + WS_ENORM);
  u16*   e16    = (u16*)(ws + WS_E16);

  // 3 dispatches: eprep(+zero) -> main -> newfin.
  vq_eprep<<<dim3(256), dim3(256), 0, stream>>>(E, enorm, e16, counts);
  vq_main<<<dim3(1024), dim3(256), 0, stream>>>(z, E, e16, enorm,
                                                embsum, loss_s, counts,
                                                out + O_ZQ, out + O_IDX);
  vq_newfin<<<dim3(K_), dim3(256), 0, stream>>>(ema_cs, counts, ema_es, embsum,
                                                loss_s, out + O_LOSS, out + O_NCS,
                                                out + O_EMB, out + O_NES);
}